// Round 10
// baseline (6675.942 us; speedup 1.0000x reference)
//
#include <hip/hip_runtime.h>
#include <math.h>

#pragma clang fp contract(off)

#define BB 64      // batch
#define N_IN 64
#define N_E 256
#define N_I 64
#define N_OUT 10

__device__ inline unsigned long long rfl64(unsigned long long x) {
  unsigned int lo = __builtin_amdgcn_readfirstlane((unsigned int)x);
  unsigned int hi = __builtin_amdgcn_readfirstlane((unsigned int)(x >> 32));
  return (((unsigned long long)hi) << 32) | (unsigned long long)lo;
}

// Round-9 structure (bit-exact, 6.08 ms) with the per-step s_barrier REPLACED
// by an LDS tag-polling exchange. Rationale: r1->r4 shows per-step cost scales
// with barrier-PHASE count (2 phases=3.57us, 1=1.52us) independent of interior
// work; every other lever (vmcnt drain, LDS ops, DVFS, topology) is falsified.
// Remaining suspect: s_barrier sleep/wake on a CU with no other resident waves
// (in GEMMs other blocks hide it; here the CU idles through it 4000 times).
// Protocol: wave w publishes pEI/kow partials -> s_waitcnt lgkmcnt(0) ->
// publishes tag=t+1 into sTag[t&1][w]. All waves spin on the four tags (one
// volatile b32x4 LDS round, broadcast) until all == t+1, then read partials.
// Safety: every wave's step-t+1 publish requires all step-t partials (I-LIF
// dependency), so inter-wave skew < 1 step -> 2-deep slot buffering (t&1) is
// race-free; tags strictly increase (stale slot holds t-1, never t+1);
// data-before-tag via lgkmcnt(0); publish-before-poll each step -> no deadlock.
// All fp accumulation orders byte-identical to r9 (ascending within word,
// ((x0+x1)+x2)+x3 combines, zero-slot +0.0f, delayed-O, W0 uniform skip).
__global__ __launch_bounds__(256, 1) void ping_kernel(
    const float* __restrict__ g_in,   // [T,64,64]
    const float* __restrict__ g_W0,   // [64,256]  clamp >=0 at use
    const float* __restrict__ g_W1,   // [256,10]  clamp >=0 at stage
    const float* __restrict__ g_Wee,  // [256,256]
    const float* __restrict__ g_Wei,  // [256,64]
    const float* __restrict__ g_Wie,  // [64,256]
    float* __restrict__ g_out,        // [64,10]
    int T, float dA, float dG)
{
  const int tid  = threadIdx.x;
  const int lane = tid & 63;
  const int wav  = tid >> 6;
  const int b    = blockIdx.x;
  const int col  = (lane < N_OUT) ? lane : 0;

  __shared__ float sWie[N_I * N_E];          // 64 KB  [j][e]
  __shared__ float sWei[N_E * N_I];          // 64 KB  [j][i]
  __shared__ float sW1[N_E * N_OUT];         // 10 KB  [j][o], clamped
  __shared__ float sP[2][4][64];             // E->I word partials (slot t&1)
  __shared__ float sKo[2][4][16];            // E->O word partials (slot t&1)
  __shared__ unsigned sTag[2][4];            // publish tags (slot t&1)
  __shared__ unsigned long long sME[2][4];   // E masks (wee fallback only)
  __shared__ float sZero[4];
  __shared__ int sWee;

  // ---- one-time staging ----
  {
    const float4* s0 = (const float4*)g_Wie; float4* d0 = (float4*)sWie;
    for (int k = tid; k < (N_I * N_E) / 4; k += 256) d0[k] = s0[k];
    const float4* s1 = (const float4*)g_Wei; float4* d1 = (float4*)sWei;
    for (int k = tid; k < (N_E * N_I) / 4; k += 256) d1[k] = s1[k];
    for (int k = tid; k < N_E * N_OUT; k += 256) sW1[k] = fmaxf(g_W1[k], 0.f);
  }
  if (tid < 4) { sME[0][tid] = 0ull; sME[1][tid] = 0ull; sZero[tid] = 0.f; }
  if (tid < 8) sTag[tid >> 2][tid & 3] = 0u;
  if (tid == 0) sWee = 0;
  // detect all-zero W_ee (true for this data; skipping a zero matmul is fp-exact)
  {
    bool any = false;
    const float4* p = (const float4*)g_Wee;
    for (int k = tid; k < (N_E * N_E) / 4; k += 256) {
      float4 x = p[k];
      any |= (x.x != 0.f) | (x.y != 0.f) | (x.z != 0.f) | (x.w != 0.f);
    }
    if (__ballot(any) != 0ull && lane == 0) sWee = 1;
  }
  __syncthreads();   // one-time full barrier: staging + tag init visible
  const int wee = sWee;

  // ---- per-thread state ----
  float vE = -65.f, ge = 0.f, gi = 0.f; int rE = 0;     // E neuron = tid
  float vI = -65.f, gI = 0.f; int rI = 0;               // I neuron = lane (replicated)
  float vO = -65.f, gO = 0.f, accO = 0.f; int rO = 0;   // output (replicated)

  unsigned long long mE = 0ull;   // own E word, s_e(t-1)
  unsigned long long mI = 0ull;   // I mask, s_i(t-1) (replicated in-register)
  unsigned long long we0 = 0ull, we1 = 0ull, we2 = 0ull, we3 = 0ull;  // wee only

  float cur = g_in[b * N_IN + lane];
  float n1  = g_in[((T > 1 ? 1 : 0) * BB + b) * N_IN + lane];

  for (int t = 0; t < T; ++t) {
    const int slot = t & 1;
    const int tp = (t + 2 < T) ? (t + 2) : (T - 1);
    float n2 = g_in[(tp * BB + b) * N_IN + lane];   // prefetch t+2

    const unsigned long long mIn = __ballot(cur != 0.f);

    // ---- W0 global loads, early issue (uniform skip on no-input steps) ----
    unsigned long long aRem = 0ull;
    bool va[4] = {false, false, false, false};
    float fw[4];
    if (mIn) {
      unsigned long long a = mIn;
      int ja[4];
#pragma unroll
      for (int k = 0; k < 4; ++k) {
        va[k] = (a != 0ull); ja[k] = va[k] ? (__ffsll(a) - 1) : 0; a &= (a - 1ull);
      }
      aRem = a;
#pragma unroll
      for (int k = 0; k < 4; ++k) fw[k] = g_W0[ja[k] * N_E + tid];
    }

    // ---- fused LDS gather over previous masks (8 kie + 4 pEI + 4 kow slots/round) ----
    float kie = 0.f, pEI = 0.f, kow = 0.f;
    {
      unsigned long long c = mI, e = mE;
      const int base = wav * 64;
      while (c | e) {
        const float* pc[8];
#pragma unroll
        for (int k = 0; k < 8; ++k) {
          bool v = (c != 0ull); int j = v ? (__ffsll(c) - 1) : 0; c &= (c - 1ull);
          pc[k] = v ? &sWie[j * N_E + tid] : &sZero[0];
        }
        const float *q[4], *r[4];
#pragma unroll
        for (int k = 0; k < 4; ++k) {
          bool v = (e != 0ull); int j = v ? (__ffsll(e) - 1) : 0; e &= (e - 1ull);
          q[k] = v ? &sWei[(base + j) * N_I + lane] : &sZero[0];
          r[k] = v ? &sW1[(base + j) * N_OUT + col] : &sZero[0];
        }
        float fI[8], fq[4], fr[4];
#pragma unroll
        for (int k = 0; k < 8; ++k) fI[k] = *pc[k];
#pragma unroll
        for (int k = 0; k < 4; ++k) { fq[k] = *q[k]; fr[k] = *r[k]; }
#pragma unroll
        for (int k = 0; k < 8; ++k) kie += fI[k];
#pragma unroll
        for (int k = 0; k < 4; ++k) pEI += fq[k];
#pragma unroll
        for (int k = 0; k < 4; ++k) kow += fr[k];
      }
    }

    // ---- consume W0 (ascending) ----
    float kin = 0.f;
    if (mIn) {
#pragma unroll
      for (int k = 0; k < 4; ++k) kin += va[k] ? fmaxf(fw[k], 0.f) : 0.f;
      while (aRem) {
        int j = __ffsll(aRem) - 1; aRem &= (aRem - 1ull);
        kin += fmaxf(g_W0[j * N_E + tid], 0.f);
      }
    }

    // ---- E<-E fallback (dead for this data) ----
    float kee = 0.f;
    if (wee) {
      unsigned long long m0 = we0, m1 = we1, m2 = we2, m3 = we3;
      while (m0 | m1 | m2 | m3) {
        bool h0 = (m0 != 0ull), h1 = (m1 != 0ull), h2 = (m2 != 0ull), h3 = (m3 != 0ull);
        int idx = 0;
        if (h0)      { idx = __ffsll(m0) - 1;       m0 &= (m0 - 1ull); }
        else if (h1) { idx = 64 + __ffsll(m1) - 1;  m1 &= (m1 - 1ull); }
        else if (h2) { idx = 128 + __ffsll(m2) - 1; m2 &= (m2 - 1ull); }
        else if (h3) { idx = 192 + __ffsll(m3) - 1; m3 &= (m3 - 1ull); }
        kee += g_Wee[idx * N_E + tid];
      }
    }

    // ---- E LIF (COBA, C_m=1, g_L=0.05, ref=12) ----
    ge = ((ge + kin) + kee) * dA;
    gi = (gi + kie) * dG;
    {
      float t2 = ge * (0.f - vE);
      float t3 = gi * (-80.f - vE);
      float Itot = t2 + t3;
      float dv = 0.25f * ((-0.05f) * (vE - (-65.f)) + Itot);
      dv = dv * 0.0125f + dv * 0.9875f;      // _scale_grad forward (not fp-identity)
      vE = fmaxf(vE + dv, -200.f);
      rE = rE - 1; if (rE < 0) rE = 0;
      bool can = (rE == 0);
      bool sE = ((vE - (-50.f)) >= 0.f) && can;
      vE = (sE || !can) ? -65.f : vE;
      rE = sE ? 12 : rE;
      unsigned long long fresh = __ballot(sE);
      if (wee && lane == 0) sME[slot][wav] = fresh;
      mE = fresh;
    }

    // ---- publish partials, then tag (data-before-tag via lgkmcnt drain) ----
    sP[slot][wav][lane] = pEI;
    if (lane < 16) sKo[slot][wav][lane] = kow;
    asm volatile("s_waitcnt lgkmcnt(0)" ::: "memory");
    if (lane == 0) *((volatile unsigned*)&sTag[slot][wav]) = (unsigned)(t + 1);

    // ---- poll all four tags (replaces s_barrier) ----
    {
      const unsigned want = (unsigned)(t + 1);
      volatile unsigned* vt = &sTag[slot][0];
      while (true) {
        unsigned a0 = vt[0], a1 = vt[1], a2 = vt[2], a3 = vt[3];
        if ((((a0 ^ want) | (a1 ^ want)) | ((a2 ^ want) | (a3 ^ want))) == 0u) break;
      }
      asm volatile("" ::: "memory");   // no hoisting of partial reads above poll
    }

    // ---- read partials (one co-issued LDS round) ----
    float p0 = sP[slot][0][lane], p1 = sP[slot][1][lane];
    float p2 = sP[slot][2][lane], p3 = sP[slot][3][lane];
    float k0 = sKo[slot][0][col], k1 = sKo[slot][1][col];
    float k2 = sKo[slot][2][col], k3 = sKo[slot][3][col];

    // ---- I LIF (replicated; C_m=0.5, g_L=0.1, ref=6) ----
    {
      float p = ((p0 + p1) + p2) + p3;
      gI = (gI + p) * dA;
      float Ii = gI * (0.f - vI);
      float dvi = 0.5f * ((-0.1f) * (vI - (-65.f)) + Ii);
      dvi = dvi * 0.0125f + dvi * 0.9875f;
      vI = fmaxf(vI + dvi, -200.f);
      rI = rI - 1; if (rI < 0) rI = 0;
      bool canI = (rI == 0);
      bool sI = ((vI - (-50.f)) >= 0.f) && canI;
      vI = (sI || !canI) ? -65.f : vI;
      rI = sI ? 6 : rI;
      mI = __ballot(sI);
    }

    // ---- O LIF (replicated, step t-1; iter 0 = exact fp no-op) ----
    {
      float ko = ((k0 + k1) + k2) + k3;
      gO = (gO + ko) * dA;
      float Io = gO * (0.f - vO);
      float dvo = 0.25f * ((-0.05f) * (vO - (-65.f)) + Io);
      dvo = dvo * 0.0125f + dvo * 0.9875f;
      vO = fmaxf(vO + dvo, -200.f);
      rO = rO - 1; if (rO < 0) rO = 0;
      bool canO = (rO == 0);
      bool sO = ((vO - (-50.f)) >= 0.f) && canO;
      vO = (sO || !canO) ? -65.f : vO;
      rO = sO ? 12 : rO;
      accO += sO ? 1.f : 0.f;
    }

    if (wee) {
      we0 = rfl64(sME[slot][0]); we1 = rfl64(sME[slot][1]);
      we2 = rfl64(sME[slot][2]); we3 = rfl64(sME[slot][3]);
    }

    cur = n1; n1 = n2;
  }

  // ---- drain: O step T-1 over s_e(T-1) (own word in mE) ----
  {
    float kd = 0.f;
    unsigned long long e = mE;
    const int base = wav * 64;
    while (e) {
      const float* r[4];
#pragma unroll
      for (int k = 0; k < 4; ++k) {
        bool v = (e != 0ull); int j = v ? (__ffsll(e) - 1) : 0; e &= (e - 1ull);
        r[k] = v ? &sW1[(base + j) * N_OUT + col] : &sZero[0];
      }
      float fr[4];
#pragma unroll
      for (int k = 0; k < 4; ++k) fr[k] = *r[k];
#pragma unroll
      for (int k = 0; k < 4; ++k) kd += fr[k];
    }
    __syncthreads();
    sP[0][wav][lane] = kd;
    __syncthreads();
    float ko = ((sP[0][0][col] + sP[0][1][col]) + sP[0][2][col]) + sP[0][3][col];
    gO = (gO + ko) * dA;
    float Io = gO * (0.f - vO);
    float dvo = 0.25f * ((-0.05f) * (vO - (-65.f)) + Io);
    dvo = dvo * 0.0125f + dvo * 0.9875f;
    vO = fmaxf(vO + dvo, -200.f);
    rO = rO - 1; if (rO < 0) rO = 0;
    bool canO = (rO == 0);
    bool sO = ((vO - (-50.f)) >= 0.f) && canO;
    accO += sO ? 1.f : 0.f;
  }

  if (wav == 0 && lane < N_OUT) g_out[b * N_OUT + lane] = accO;
}

extern "C" void kernel_launch(void* const* d_in, const int* in_sizes, int n_in,
                              void* d_out, int out_size, void* d_ws, size_t ws_size,
                              hipStream_t stream) {
  const float* g_in  = (const float*)d_in[0];
  const float* g_W0  = (const float*)d_in[1];
  const float* g_W1  = (const float*)d_in[2];
  const float* g_Wee = (const float*)d_in[3];
  const float* g_Wei = (const float*)d_in[4];
  const float* g_Wie = (const float*)d_in[5];
  float* out = (float*)d_out;
  int T = in_sizes[0] / (BB * N_IN);
  float dA = (float)exp(-0.25 / 2.0);   // tau_ampa = 2.0
  float dG = (float)exp(-0.25 / 9.0);   // tau_gaba = 9.0
  ping_kernel<<<dim3(BB), dim3(256), 0, stream>>>(g_in, g_W0, g_W1, g_Wee, g_Wei, g_Wie, out, T, dA, dG);
}

// Round 11
// 5295.107 us; speedup vs baseline: 1.2608x; 1.2608x over previous
//
#include <hip/hip_runtime.h>
#include <math.h>

#pragma clang fp contract(off)

#define BB 64      // batch
#define N_IN 64
#define N_E 256
#define N_I 64
#define N_OUT 10

__device__ inline unsigned long long rfl64(unsigned long long x) {
  unsigned int lo = __builtin_amdgcn_readfirstlane((unsigned int)x);
  unsigned int hi = __builtin_amdgcn_readfirstlane((unsigned int)(x >> 32));
  return (((unsigned long long)hi) << 32) | (unsigned long long)lo;
}

// r9/r10 math (bit-exact) with the cross-wave recurrence cycle shortened:
//  (1) EARLY PUBLISH: the E-word gather (pEI/kow, 4 slots) runs FIRST and the
//      partials + tag publish immediately after it — before kie, W0 consume,
//      and the E-LIF. pEI/kow are the only cross-wave data (E masks stay
//      wave-local), so this is legal; other waves' polls then succeed on the
//      first read because the tag is ~400 cy earlier than in r9/r10.
//  (2) W0 PREFETCH 1 STEP AHEAD: step t+1's input mask comes from n1 (already
//      resident), so its W0 row loads issue at the bottom of step t — the
//      same-step vmcnt wait disappears from the chain.
//  (3) SCALAR-SELECT GATHERS: slot validity is wave-uniform, so the row base
//      is selected scalar (s_cselect) against a 256-entry LDS zero row; per
//      slot only one v_add + ds_read remains on the vector pipe.
// Sync protocol identical to r10 (tag after lgkmcnt(0) drain; poll before
// partial reads; 2-slot buffering; skew<1 step by the I-LIF dependency).
// All fp accumulation orders byte-identical to the bit-exact r9 kernel.
__global__ __launch_bounds__(256, 1) void ping_kernel(
    const float* __restrict__ g_in,   // [T,64,64]
    const float* __restrict__ g_W0,   // [64,256]  clamp >=0 at use
    const float* __restrict__ g_W1,   // [256,10]  clamp >=0 at stage
    const float* __restrict__ g_Wee,  // [256,256]
    const float* __restrict__ g_Wei,  // [256,64]
    const float* __restrict__ g_Wie,  // [64,256]
    float* __restrict__ g_out,        // [64,10]
    int T, float dA, float dG)
{
  const int tid  = threadIdx.x;
  const int lane = tid & 63;
  const int wav  = tid >> 6;
  const int b    = blockIdx.x;
  const int col  = (lane < N_OUT) ? lane : 0;

  __shared__ float sWie[N_I * N_E];          // 64 KB  [j][e]
  __shared__ float sWei[N_E * N_I];          // 64 KB  [j][i]
  __shared__ float sW1[N_E * N_OUT];         // 10 KB  [j][o], clamped
  __shared__ float sZeroRow[256];            // 1 KB zero row (tid-indexable)
  __shared__ float sP[2][4][64];             // E->I word partials (slot t&1)
  __shared__ float sKo[2][4][16];            // E->O word partials (slot t&1)
  __shared__ unsigned sTag[2][4];            // publish tags (slot t&1)
  __shared__ unsigned long long sME[2][4];   // E masks (wee fallback only)
  __shared__ int sWee;

  // ---- one-time staging ----
  {
    const float4* s0 = (const float4*)g_Wie; float4* d0 = (float4*)sWie;
    for (int k = tid; k < (N_I * N_E) / 4; k += 256) d0[k] = s0[k];
    const float4* s1 = (const float4*)g_Wei; float4* d1 = (float4*)sWei;
    for (int k = tid; k < (N_E * N_I) / 4; k += 256) d1[k] = s1[k];
    for (int k = tid; k < N_E * N_OUT; k += 256) sW1[k] = fmaxf(g_W1[k], 0.f);
  }
  sZeroRow[tid] = 0.f;
  if (tid < 4) { sME[0][tid] = 0ull; sME[1][tid] = 0ull; }
  if (tid < 8) sTag[tid >> 2][tid & 3] = 0u;
  if (tid == 0) sWee = 0;
  // detect all-zero W_ee (true for this data; skipping a zero matmul is fp-exact)
  {
    bool any = false;
    const float4* p = (const float4*)g_Wee;
    for (int k = tid; k < (N_E * N_E) / 4; k += 256) {
      float4 x = p[k];
      any |= (x.x != 0.f) | (x.y != 0.f) | (x.z != 0.f) | (x.w != 0.f);
    }
    if (__ballot(any) != 0ull && lane == 0) sWee = 1;
  }
  __syncthreads();
  const int wee = sWee;

  // ---- per-thread state ----
  float vE = -65.f, ge = 0.f, gi = 0.f; int rE = 0;     // E neuron = tid
  float vI = -65.f, gI = 0.f; int rI = 0;               // I neuron = lane (replicated)
  float vO = -65.f, gO = 0.f, accO = 0.f; int rO = 0;   // output (replicated)

  unsigned long long mE = 0ull;   // own E word, s_e(t-1) (wave-local)
  unsigned long long mI = 0ull;   // I mask, s_i(t-1) (replicated in-register)
  unsigned long long we0 = 0ull, we1 = 0ull, we2 = 0ull, we3 = 0ull;  // wee only

  // input pipeline + W0 prefetch pipeline (loads for step t issued at t-1)
  float cur = g_in[b * N_IN + lane];
  float n1  = g_in[((T > 1 ? 1 : 0) * BB + b) * N_IN + lane];

  unsigned long long mInC = __ballot(cur != 0.f);   // step-0 input mask
  unsigned long long aRemC = 0ull;
  bool vaC[4] = {false, false, false, false};
  float fwC[4];
  if (mInC) {
    unsigned long long a = mInC;
    int ja[4];
#pragma unroll
    for (int k = 0; k < 4; ++k) {
      vaC[k] = (a != 0ull); ja[k] = vaC[k] ? (__ffsll(a) - 1) : 0; a &= (a - 1ull);
    }
    aRemC = a;
#pragma unroll
    for (int k = 0; k < 4; ++k) fwC[k] = g_W0[ja[k] * N_E + tid];
  }

  for (int t = 0; t < T; ++t) {
    const int slot = t & 1;
    const int tp = (t + 2 < T) ? (t + 2) : (T - 1);
    float n2 = g_in[(tp * BB + b) * N_IN + lane];   // prefetch t+2

    // ---- (1) E-word gather FIRST: pEI/kow over own word of s_e(t-1) ----
    float pEI = 0.f, kow = 0.f;
    {
      unsigned long long e = mE;
      const int base = wav * 64;
      while (e) {
        const float *qb[4], *rb[4];
#pragma unroll
        for (int k = 0; k < 4; ++k) {
          bool v = (e != 0ull); int j = v ? (__ffsll(e) - 1) : 0; e &= (e - 1ull);
          qb[k] = v ? &sWei[(base + j) * N_I] : sZeroRow;   // uniform base select
          rb[k] = v ? &sW1[(base + j) * N_OUT] : sZeroRow;
        }
        float fq[4], fr[4];
#pragma unroll
        for (int k = 0; k < 4; ++k) { fq[k] = qb[k][lane]; fr[k] = rb[k][col]; }
#pragma unroll
        for (int k = 0; k < 4; ++k) pEI += fq[k];
#pragma unroll
        for (int k = 0; k < 4; ++k) kow += fr[k];
      }
    }

    // ---- EARLY publish + tag (data-before-tag via lgkmcnt drain) ----
    sP[slot][wav][lane] = pEI;
    if (lane < 16) sKo[slot][wav][lane] = kow;
    asm volatile("s_waitcnt lgkmcnt(0)" ::: "memory");
    if (lane == 0) *((volatile unsigned*)&sTag[slot][wav]) = (unsigned)(t + 1);

    // ---- kie gather (own-pipe work while other waves publish) ----
    float kie = 0.f;
    {
      unsigned long long c = mI;
      while (c) {
        const float* pb[8];
#pragma unroll
        for (int k = 0; k < 8; ++k) {
          bool v = (c != 0ull); int j = v ? (__ffsll(c) - 1) : 0; c &= (c - 1ull);
          pb[k] = v ? &sWie[j * N_E] : sZeroRow;
        }
        float fI[8];
#pragma unroll
        for (int k = 0; k < 8; ++k) fI[k] = pb[k][tid];
#pragma unroll
        for (int k = 0; k < 8; ++k) kie += fI[k];
      }
    }

    // ---- W0 consume (loads issued LAST step -> no vmcnt stall) ----
    float kin = 0.f;
    if (mInC) {
#pragma unroll
      for (int k = 0; k < 4; ++k) kin += vaC[k] ? fmaxf(fwC[k], 0.f) : 0.f;
      while (aRemC) {   // rare: >4 input spikes
        int j = __ffsll(aRemC) - 1; aRemC &= (aRemC - 1ull);
        kin += fmaxf(g_W0[j * N_E + tid], 0.f);
      }
    }

    // ---- E<-E fallback (dead for this data) ----
    float kee = 0.f;
    if (wee) {
      unsigned long long m0 = we0, m1 = we1, m2 = we2, m3 = we3;
      while (m0 | m1 | m2 | m3) {
        bool h0 = (m0 != 0ull), h1 = (m1 != 0ull), h2 = (m2 != 0ull), h3 = (m3 != 0ull);
        int idx = 0;
        if (h0)      { idx = __ffsll(m0) - 1;       m0 &= (m0 - 1ull); }
        else if (h1) { idx = 64 + __ffsll(m1) - 1;  m1 &= (m1 - 1ull); }
        else if (h2) { idx = 128 + __ffsll(m2) - 1; m2 &= (m2 - 1ull); }
        else if (h3) { idx = 192 + __ffsll(m3) - 1; m3 &= (m3 - 1ull); }
        kee += g_Wee[idx * N_E + tid];
      }
    }

    // ---- E LIF (COBA, C_m=1, g_L=0.05, ref=12); mask stays wave-local ----
    ge = ((ge + kin) + kee) * dA;
    gi = (gi + kie) * dG;
    {
      float t2 = ge * (0.f - vE);
      float t3 = gi * (-80.f - vE);
      float Itot = t2 + t3;
      float dv = 0.25f * ((-0.05f) * (vE - (-65.f)) + Itot);
      dv = dv * 0.0125f + dv * 0.9875f;      // _scale_grad forward (not fp-identity)
      vE = fmaxf(vE + dv, -200.f);
      rE = rE - 1; if (rE < 0) rE = 0;
      bool can = (rE == 0);
      bool sE = ((vE - (-50.f)) >= 0.f) && can;
      vE = (sE || !can) ? -65.f : vE;
      rE = sE ? 12 : rE;
      unsigned long long fresh = __ballot(sE);
      if (wee && lane == 0) sME[slot][wav] = fresh;
      mE = fresh;
    }

    // ---- poll tags (first read should hit: tags were published early) ----
    {
      const unsigned want = (unsigned)(t + 1);
      volatile unsigned* vt = &sTag[slot][0];
      while (true) {
        unsigned a0 = vt[0], a1 = vt[1], a2 = vt[2], a3 = vt[3];
        if ((((a0 ^ want) | (a1 ^ want)) | ((a2 ^ want) | (a3 ^ want))) == 0u) break;
      }
      asm volatile("" ::: "memory");
    }

    // ---- read partials ----
    float p0 = sP[slot][0][lane], p1 = sP[slot][1][lane];
    float p2 = sP[slot][2][lane], p3 = sP[slot][3][lane];
    float k0 = sKo[slot][0][col], k1 = sKo[slot][1][col];
    float k2 = sKo[slot][2][col], k3 = sKo[slot][3][col];

    // ---- I LIF (replicated; C_m=0.5, g_L=0.1, ref=6) ----
    {
      float p = ((p0 + p1) + p2) + p3;
      gI = (gI + p) * dA;
      float Ii = gI * (0.f - vI);
      float dvi = 0.5f * ((-0.1f) * (vI - (-65.f)) + Ii);
      dvi = dvi * 0.0125f + dvi * 0.9875f;
      vI = fmaxf(vI + dvi, -200.f);
      rI = rI - 1; if (rI < 0) rI = 0;
      bool canI = (rI == 0);
      bool sI = ((vI - (-50.f)) >= 0.f) && canI;
      vI = (sI || !canI) ? -65.f : vI;
      rI = sI ? 6 : rI;
      mI = __ballot(sI);
    }

    // ---- O LIF (replicated, step t-1; iter 0 = exact fp no-op) ----
    {
      float ko = ((k0 + k1) + k2) + k3;
      gO = (gO + ko) * dA;
      float Io = gO * (0.f - vO);
      float dvo = 0.25f * ((-0.05f) * (vO - (-65.f)) + Io);
      dvo = dvo * 0.0125f + dvo * 0.9875f;
      vO = fmaxf(vO + dvo, -200.f);
      rO = rO - 1; if (rO < 0) rO = 0;
      bool canO = (rO == 0);
      bool sO = ((vO - (-50.f)) >= 0.f) && canO;
      vO = (sO || !canO) ? -65.f : vO;
      rO = sO ? 12 : rO;
      accO += sO ? 1.f : 0.f;
    }

    if (wee) {
      __syncthreads();   // fallback-only: make sME(t) visible (dead path here)
      we0 = rfl64(sME[slot][0]); we1 = rfl64(sME[slot][1]);
      we2 = rfl64(sME[slot][2]); we3 = rfl64(sME[slot][3]);
    }

    // ---- bottom: W0 prefetch for step t+1 from n1 (off critical path) ----
    mInC = __ballot(n1 != 0.f);
    aRemC = 0ull;
    vaC[0] = vaC[1] = vaC[2] = vaC[3] = false;
    if (mInC) {
      unsigned long long a = mInC;
      int ja[4];
#pragma unroll
      for (int k = 0; k < 4; ++k) {
        vaC[k] = (a != 0ull); ja[k] = vaC[k] ? (__ffsll(a) - 1) : 0; a &= (a - 1ull);
      }
      aRemC = a;
#pragma unroll
      for (int k = 0; k < 4; ++k) fwC[k] = g_W0[ja[k] * N_E + tid];
    }

    cur = n1; n1 = n2;
  }

  // ---- drain: O step T-1 over s_e(T-1) (own word in mE) ----
  {
    float kd = 0.f;
    unsigned long long e = mE;
    const int base = wav * 64;
    while (e) {
      const float* rb[4];
#pragma unroll
      for (int k = 0; k < 4; ++k) {
        bool v = (e != 0ull); int j = v ? (__ffsll(e) - 1) : 0; e &= (e - 1ull);
        rb[k] = v ? &sW1[(base + j) * N_OUT] : sZeroRow;
      }
      float fr[4];
#pragma unroll
      for (int k = 0; k < 4; ++k) fr[k] = rb[k][col];
#pragma unroll
      for (int k = 0; k < 4; ++k) kd += fr[k];
    }
    __syncthreads();
    sP[0][wav][lane] = kd;
    __syncthreads();
    float ko = ((sP[0][0][col] + sP[0][1][col]) + sP[0][2][col]) + sP[0][3][col];
    gO = (gO + ko) * dA;
    float Io = gO * (0.f - vO);
    float dvo = 0.25f * ((-0.05f) * (vO - (-65.f)) + Io);
    dvo = dvo * 0.0125f + dvo * 0.9875f;
    vO = fmaxf(vO + dvo, -200.f);
    rO = rO - 1; if (rO < 0) rO = 0;
    bool canO = (rO == 0);
    bool sO = ((vO - (-50.f)) >= 0.f) && canO;
    accO += sO ? 1.f : 0.f;
  }

  if (wav == 0 && lane < N_OUT) g_out[b * N_OUT + lane] = accO;
}

extern "C" void kernel_launch(void* const* d_in, const int* in_sizes, int n_in,
                              void* d_out, int out_size, void* d_ws, size_t ws_size,
                              hipStream_t stream) {
  const float* g_in  = (const float*)d_in[0];
  const float* g_W0  = (const float*)d_in[1];
  const float* g_W1  = (const float*)d_in[2];
  const float* g_Wee = (const float*)d_in[3];
  const float* g_Wei = (const float*)d_in[4];
  const float* g_Wie = (const float*)d_in[5];
  float* out = (float*)d_out;
  int T = in_sizes[0] / (BB * N_IN);
  float dA = (float)exp(-0.25 / 2.0);   // tau_ampa = 2.0
  float dG = (float)exp(-0.25 / 9.0);   // tau_gaba = 9.0
  ping_kernel<<<dim3(BB), dim3(256), 0, stream>>>(g_in, g_W0, g_W1, g_Wee, g_Wei, g_Wie, out, T, dA, dG);
}